// Round 1
// baseline (421.851 us; speedup 1.0000x reference)
//
#include <hip/hip_runtime.h>
#include <hip/hip_bf16.h>
#include <stdint.h>

// Problem constants
#define B_  4
#define S_  2048
#define D_  1024
#define H_  16
#define DH_ 64
#define N3_ 3072   // 3*D

typedef __attribute__((ext_vector_type(8))) short  short8;   // 8 bf16 (4 VGPRs)
typedef __attribute__((ext_vector_type(8))) unsigned short ushort8;
typedef __attribute__((ext_vector_type(4))) float  float4v;  // 4 fp32 acc

__device__ __forceinline__ float bf2f(unsigned short u) {
    union { unsigned int i; float f; } c; c.i = ((unsigned int)u) << 16; return c.f;
}
__device__ __forceinline__ unsigned short f2bf(float f) {
    union { float f; unsigned int i; } c; c.f = f;
    unsigned int x = c.i;
    return (unsigned short)((x + 0x7FFFu + ((x >> 16) & 1u)) >> 16);  // RNE
}
__device__ __forceinline__ unsigned short f2bf_hu(float f) {   // half-up (cheap)
    union { float f; unsigned int i; } c; c.f = f;
    return (unsigned short)((c.i + 0x8000u) >> 16);
}

// async global->LDS DMA, 16B per lane; LDS dest = wave-uniform base + lane*16
__device__ __forceinline__ void gll16(const void* g, void* l) {
    __builtin_amdgcn_global_load_lds(
        (const __attribute__((address_space(1))) unsigned int*)g,
        (__attribute__((address_space(3))) unsigned int*)l, 16, 0, 0);
}

// ---------------------------------------------------------------------------
// fp32 -> bf16 elementwise (x). 8 elems/thread.
// ---------------------------------------------------------------------------
__global__ __launch_bounds__(256) void convert_x(
    const float* __restrict__ in, unsigned short* __restrict__ out, int n8)
{
    int g = blockIdx.x * 256 + threadIdx.x;
    if (g >= n8) return;
    const float4* p = (const float4*)(in + (size_t)g * 8);
    float4 a = p[0], b = p[1];
    ushort8 o;
    o[0] = f2bf(a.x); o[1] = f2bf(a.y); o[2] = f2bf(a.z); o[3] = f2bf(a.w);
    o[4] = f2bf(b.x); o[5] = f2bf(b.y); o[6] = f2bf(b.z); o[7] = f2bf(b.w);
    *(ushort8*)(out + (size_t)g * 8) = o;
}

// ---------------------------------------------------------------------------
// fp32 [K][N] -> bf16 [N][K] transpose (weights). 32x32 LDS tile, 256 thr.
// ---------------------------------------------------------------------------
__global__ __launch_bounds__(256) void convert_wT(
    const float* __restrict__ w, unsigned short* __restrict__ wt, int K, int N)
{
    __shared__ float t[32][33];
    const int row = threadIdx.x >> 5;   // 0..7
    const int col = threadIdx.x & 31;   // 0..31
    const int n0 = blockIdx.x * 32;
    const int k0 = blockIdx.y * 32;
#pragma unroll
    for (int i = 0; i < 4; ++i)
        t[row + 8 * i][col] = w[(size_t)(k0 + row + 8 * i) * N + n0 + col];
    __syncthreads();
#pragma unroll
    for (int i = 0; i < 4; ++i)
        wt[(size_t)(n0 + row + 8 * i) * K + k0 + col] = f2bf(t[col][row + 8 * i]);
}

// ---------------------------------------------------------------------------
// bf16 MFMA GEMM: C[M,N] = A[M,K] @ Bt[N,K]^T + bias.
// 128x128 tile, BK=64, 4 waves, each wave 64x64 (4x4 MFMA tiles).
// (unchanged this round — m97-structure, XOR-swizzled global_load_lds staging)
// MODE 0: scatter to q/k [B][H][S][DH] and vT [B][H][DH][S] bf16 (N=3072).
// MODE 1: fp32 out [M][N] (N=1024).
// ---------------------------------------------------------------------------
template <int MODE>
__global__ __launch_bounds__(256) void gemm_bt(
    const unsigned short* __restrict__ a, const unsigned short* __restrict__ bt,
    const float* __restrict__ bias,
    unsigned short* __restrict__ q, unsigned short* __restrict__ k,
    unsigned short* __restrict__ v, float* __restrict__ out,
    int K, int N)
{
    __shared__ unsigned short As[128][64];   // unpadded: 16 KB each
    __shared__ unsigned short Bs[128][64];

    const int tid  = threadIdx.x;
    const int wave = tid >> 6;
    const int lane = tid & 63;
    const int col  = lane & 15;
    const int quad = lane >> 4;
    const int wm   = (wave & 1) * 64;
    const int wn   = (wave >> 1) * 64;

    const int m0 = blockIdx.y * 128;
    const int n0 = blockIdx.x * 128;

    const int srow0 = wave * 32 + (lane >> 3);
    const int scg   = (lane & 7) ^ (lane >> 3);

    float4v acc[4][4] = {};

    for (int kt = 0; kt < K; kt += 64) {
#pragma unroll
        for (int c = 0; c < 4; ++c) {
            int row = srow0 + c * 8;
            gll16(a  + (size_t)(m0 + row) * K + kt + scg * 8,
                  (char*)As + wave * 4096 + c * 1024);
            gll16(bt + (size_t)(n0 + row) * K + kt + scg * 8,
                  (char*)Bs + wave * 4096 + c * 1024);
        }
        __syncthreads();   // drains vmcnt (incl. global_load_lds)

#pragma unroll
        for (int ks = 0; ks < 64; ks += 32) {
            const int sa = (((ks >> 3) + quad) ^ (col & 7)) * 8;  // swizzled offset
            short8 af[4], bf[4];
#pragma unroll
            for (int mi = 0; mi < 4; ++mi)
                af[mi] = *(const short8*)&As[wm + mi * 16 + col][sa];
#pragma unroll
            for (int ni = 0; ni < 4; ++ni)
                bf[ni] = *(const short8*)&Bs[wn + ni * 16 + col][sa];
#pragma unroll
            for (int mi = 0; mi < 4; ++mi)
#pragma unroll
                for (int ni = 0; ni < 4; ++ni)
                    acc[mi][ni] = __builtin_amdgcn_mfma_f32_16x16x32_bf16(
                        af[mi], bf[ni], acc[mi][ni], 0, 0, 0);
        }
        __syncthreads();
    }

#pragma unroll
    for (int mi = 0; mi < 4; ++mi) {
#pragma unroll
        for (int ni = 0; ni < 4; ++ni) {
            int n = n0 + wn + ni * 16 + col;
            float bv = bias[n];
#pragma unroll
            for (int r = 0; r < 4; ++r) {
                int m = m0 + wm + mi * 16 + quad * 4 + r;
                float val = acc[mi][ni][r] + bv;
                if (MODE == 0) {
                    int which = n >> 10;          // 0=Q 1=K 2=V
                    int h  = (n & 1023) >> 6;
                    int dh = n & 63;
                    int bb = m >> 11;
                    int s  = m & 2047;
                    size_t off;
                    if (which == 2)   // V stored transposed: [b][h][dh][s]
                        off = (((size_t)bb * H_ + h) * DH_ + dh) * S_ + s;
                    else
                        off = (((size_t)bb * H_ + h) * S_ + s) * DH_ + dh;
                    unsigned short* dst = (which == 0) ? q : ((which == 1) ? k : v);
                    dst[off] = f2bf(val);
                } else {
                    out[(size_t)m * N + n] = val;
                }
            }
        }
    }
}

// ---------------------------------------------------------------------------
// Flash-style MFMA attention, v6.
// Changes vs v5 (164 us, MfmaUtil 17%):
//  1. Double-buffered Ks/Vt staging (T3 minimal 2-phase): STAGE(t+1) issued
//     right after the barrier, ONE __syncthreads per kv-tile. The barrier's
//     vmcnt drain now waits on loads issued a full compute-phase earlier.
//  2. Swapped QK^T: mfma(Kfrag, Qfrag) -> scores land as S[key][qrow]
//     (operand fragments are byte-identical to v5, only roles swap). This
//     makes mask loads 4x dwordx4 (was 16x dword), P-store 4x ds_write_b64
//     packed pairs (was 16x ds_write_b16), and row-sum a single per-lane
//     scalar (2 shfl reduce, was 16).
//  LDS: 40 KB -> 4 blocks/CU.
// Fragment layouts (validated in-kernel, prior session):
//   A[m][k]: m=lane&15, k=quad*8+j ; B[k][n]: n=lane&15, k=quad*8+j
//   C/D    : col(n)=lane&15, row(m)=quad*4+reg
// ---------------------------------------------------------------------------
__global__ __launch_bounds__(256) void attn_mfma(
    const unsigned short* __restrict__ q, const unsigned short* __restrict__ k,
    const unsigned short* __restrict__ vT, const int* __restrict__ mask,
    unsigned short* __restrict__ ctx)
{
    __shared__ unsigned short Ks[2][64][64];   // [buf][key][dh], swizzled granules
    __shared__ unsigned short Vt[2][64][64];   // [buf][dh][key], swizzled granules
    __shared__ unsigned short Ps[4][16][64];   // per-wave P^T [qrow][key], swizzled

    const int tid  = threadIdx.x;
    const int wave = tid >> 6;
    const int lane = tid & 63;
    const int col  = lane & 15;
    const int quad = lane >> 4;

    const int h  = blockIdx.y;
    const int bb = blockIdx.z;
    const int q0 = blockIdx.x * 64 + wave * 16;
    const int kvbase = ((bb * H_ + h) * S_) * DH_;
    const int vtbase = ((bb * H_ + h) * DH_) * S_;

    // Q B-fragments, pre-scaled by 1/sqrt(DH) * log2(e)
    const float SC = 0.18033688011112042f;
    const unsigned short* qrow = q + kvbase + (q0 + col) * DH_;
    ushort8 qr0 = *(const ushort8*)(qrow + quad * 8);
    ushort8 qr1 = *(const ushort8*)(qrow + 32 + quad * 8);
    short8 qa0, qa1;
#pragma unroll
    for (int j = 0; j < 8; ++j) {
        qa0[j] = (short)f2bf(bf2f(qr0[j]) * SC);
        qa1[j] = (short)f2bf(bf2f(qr1[j]) * SC);
    }
    const float MASKED = -1442.6951f;   // -1000*log2(e): exp2 -> exactly 0

    // mask row pointer: lane (col,quad) covers qrow = q0+col,
    // keys key0 + sub*16 + quad*4 + (0..3)  -> int4 loads
    const int* mrow = mask + ((size_t)bb * S_ + q0 + col) * S_ + quad * 4;

    // staging geometry (per wave pair): rows [sw2*32, sw2*32+32)
    const int sw2   = wave & 1;
    const int srow0 = sw2 * 32 + (lane >> 3);
    const int scg   = (lane & 7) ^ (lane >> 3);
    const int sw0   = (quad ^ (col & 7)) * 8;        // swizzled frag offset, lo granule
    const int sw1   = ((4 + quad) ^ (col & 7)) * 8;  // hi granule

    float4v oacc[4] = {};
    float rsum = 0.f;

    auto STAGE = [&](int buf, int kt) {
        const int key0 = kt * 64;
#pragma unroll
        for (int c = 0; c < 4; ++c) {
            int r = srow0 + c * 8;
            if (wave < 2)
                gll16(k + kvbase + (key0 + r) * DH_ + scg * 8,
                      (char*)Ks + buf * 8192 + sw2 * 4096 + c * 1024);
            else
                gll16(vT + vtbase + r * S_ + key0 + scg * 8,
                      (char*)Vt + buf * 8192 + sw2 * 4096 + c * 1024);
        }
    };

    auto LOADMASK = [&](int4 (&m)[4], int kt) {
        const int* p = mrow + kt * 64;
#pragma unroll
        for (int sub = 0; sub < 4; ++sub)
            m[sub] = *(const int4*)(p + sub * 16);
    };

    auto TILE = [&](int buf, const int4 (&mu)[4]) {
        // ---- QK^T swapped: C[key][qrow]; key = sub*16+quad*4+r, qrow = col
        float4v sc[4];
#pragma unroll
        for (int sub = 0; sub < 4; ++sub) {
            short8 a0 = *(const short8*)&Ks[buf][sub * 16 + col][sw0];
            short8 a1 = *(const short8*)&Ks[buf][sub * 16 + col][sw1];
            float4v acs = {};
            acs = __builtin_amdgcn_mfma_f32_16x16x32_bf16(a0, qa0, acs, 0, 0, 0);
            acs = __builtin_amdgcn_mfma_f32_16x16x32_bf16(a1, qa1, acs, 0, 0, 0);
            sc[sub] = acs;
        }
        // ---- mask + exp2 + row-sum + pack pairs + P^T store (swizzled b64)
#pragma unroll
        for (int sub = 0; sub < 4; ++sub) {
            int mm[4] = { mu[sub].x, mu[sub].y, mu[sub].z, mu[sub].w };
            float p[4];
#pragma unroll
            for (int r = 0; r < 4; ++r) {
                float s = (mm[r] == 0) ? MASKED : sc[sub][r];
                p[r] = __builtin_amdgcn_exp2f(s);
                rsum += p[r];
            }
            unsigned int u0 = ((unsigned int)f2bf_hu(p[1]) << 16) | f2bf_hu(p[0]);
            unsigned int u1 = ((unsigned int)f2bf_hu(p[3]) << 16) | f2bf_hu(p[2]);
            // keys 16*sub+4*quad.. +3 at row col: granule 2*sub+(quad>>1),
            // byte-in-granule 8*(quad&1); XOR-swizzle granule with (col&7)
            int sg = (2 * sub + (quad >> 1)) ^ (col & 7);
            uint2 w; w.x = u0; w.y = u1;
            *(uint2*)((char*)&Ps[wave][0][0] + col * 128 + sg * 16 + (quad & 1) * 8) = w;
        }
        // no barrier: Ps is wave-private (lgkmcnt ordering suffices)
        short8 pa0 = *(const short8*)&Ps[wave][col][sw0];
        short8 pa1 = *(const short8*)&Ps[wave][col][sw1];
        // ---- PV: O(16x64) += P(16x64) * V(64x64)
#pragma unroll
        for (int n = 0; n < 4; ++n) {
            short8 vb0 = *(const short8*)&Vt[buf][n * 16 + col][sw0];
            short8 vb1 = *(const short8*)&Vt[buf][n * 16 + col][sw1];
            oacc[n] = __builtin_amdgcn_mfma_f32_16x16x32_bf16(pa0, vb0, oacc[n], 0, 0, 0);
            oacc[n] = __builtin_amdgcn_mfma_f32_16x16x32_bf16(pa1, vb1, oacc[n], 0, 0, 0);
        }
    };

    // ---- pipelined main loop: 1 barrier per kv-tile, prefetch depth 1 ----
    int4 mA[4], mB[4];
    LOADMASK(mA, 0);
    STAGE(0, 0);
#pragma unroll 1
    for (int kt2 = 0; kt2 < S_ / 128; ++kt2) {
        const int ke = kt2 * 2, ko = ke + 1;
        __syncthreads();                    // tile ke staged; buf1 reads (prev) done
        LOADMASK(mB, ko);
        STAGE(1, ko);                       // hidden under TILE(0)
        TILE(0, mA);
        __syncthreads();                    // tile ko staged; buf0 reads done
        if (kt2 < S_ / 128 - 1) {
            LOADMASK(mA, ke + 2);
            STAGE(0, ke + 2);               // hidden under TILE(1)
        }
        TILE(1, mB);
    }

    // ---- final row-sum reduction + normalize + store ----
    // rsum = partial sum for qrow=q0+col over this lane's keys; reduce quads
    float s = rsum;
    s += __shfl_xor(s, 16);
    s += __shfl_xor(s, 32);
    float invs = 1.0f / s;                  // full row sum for qrow = q0+col
    float inv4[4];
#pragma unroll
    for (int r = 0; r < 4; ++r)
        inv4[r] = __shfl(invs, quad * 20 + r);   // lane quad*16 + (quad*4+r)
#pragma unroll
    for (int n = 0; n < 4; ++n)
#pragma unroll
    for (int r = 0; r < 4; ++r) {
        size_t off = ((size_t)bb * S_ + (q0 + quad * 4 + r)) * D_
                   + h * DH_ + n * 16 + col;
        ctx[off] = f2bf(oacc[n][r] * inv4[r]);
    }
}

extern "C" void kernel_launch(void* const* d_in, const int* in_sizes, int n_in,
                              void* d_out, int out_size, void* d_ws, size_t ws_size,
                              hipStream_t stream)
{
    const float* x     = (const float*)d_in[0];
    const int*   mask  = (const int*)d_in[1];
    const float* w_qkv = (const float*)d_in[2];
    const float* b_qkv = (const float*)d_in[3];
    const float* w_out = (const float*)d_in[4];
    const float* b_out = (const float*)d_in[5];
    float* out = (float*)d_out;

    unsigned short* ws = (unsigned short*)d_ws;
    const size_t sz = (size_t)B_ * S_ * D_;   // 8,388,608 elements
    unsigned short* q     = ws;
    unsigned short* kk    = ws + sz;
    unsigned short* v     = ws + 2 * sz;      // vT layout [B][H][DH][S]
    unsigned short* ctx   = ws + 3 * sz;
    unsigned short* xbf   = ws + 4 * sz;
    unsigned short* wqkvT = ws + 5 * sz;                       // 3072*1024
    unsigned short* woutT = ws + 5 * sz + (size_t)N3_ * D_;    // 1024*1024

    convert_x<<<(int)(sz / (256 * 8)), 256, 0, stream>>>(x, xbf, (int)(sz / 8));
    convert_wT<<<dim3(N3_ / 32, D_ / 32), 256, 0, stream>>>(w_qkv, wqkvT, D_, N3_);
    convert_wT<<<dim3(D_ / 32, D_ / 32), 256, 0, stream>>>(w_out, woutT, D_, D_);

    gemm_bt<0><<<dim3(N3_ / 128, (B_ * S_) / 128), 256, 0, stream>>>(
        xbf, wqkvT, b_qkv, q, kk, v, nullptr, D_, N3_);

    attn_mfma<<<dim3(S_ / 64, H_, B_), 256, 0, stream>>>(q, kk, v, mask, ctx);

    gemm_bt<1><<<dim3(D_ / 128, (B_ * S_) / 128), 256, 0, stream>>>(
        ctx, woutT, b_out, nullptr, nullptr, nullptr, out, D_, D_);
}